// Round 11
// baseline (492.664 us; speedup 1.0000x reference)
//
#include <hip/hip_runtime.h>
#include <hip/hip_bf16.h>
#include <math.h>

#define D_MODEL 1024
#define NH      16
#define HD      64
#define DFF     4096
#define SEQ     1024
#define BATCH   4
#define TOK     (BATCH*SEQ)   // 4096 tokens
#define MAXSTEPS 24

typedef __hip_bfloat16 bf16;
typedef __attribute__((ext_vector_type(8))) short short8;   // 8 bf16 = one MFMA frag
typedef __attribute__((ext_vector_type(4))) float floatx4;  // MFMA acc

__device__ __forceinline__ float b2f(bf16 v){ return __bfloat162float(v); }
__device__ __forceinline__ bf16  f2b(float v){ return __float2bfloat16(v); }

__device__ __forceinline__ void gload_lds16(const bf16* g, bf16* l){
    __builtin_amdgcn_global_load_lds((const __attribute__((address_space(1))) void*)g,
                                     (__attribute__((address_space(3))) void*)l, 16, 0, 0);
}

// ---------------------------------------------------------------------------
// mfma_gemm: C = A[M,*](bf16,lda) * Bt[N,*]^T(bf16,ldb) + bias.
// 128 x TN tile, 4 waves 2x2 (wave 64 x TN/2). R12 ring pipeline
// (R-deep LDS ring via global_load_lds, counted vmcnt, 1 barrier/k-step).
// EPI: 0 fp32 | 1 bf16 | 3 gatemix (sigmoid + step-embed, reads x/orig).
// ---------------------------------------------------------------------------
template<int TN, int EPI, bool SPLITK>
__global__ __launch_bounds__(256)
void mfma_gemm(const bf16* __restrict__ A, const bf16* __restrict__ Bt,
               const float* __restrict__ bias, void* __restrict__ outv,
               void* __restrict__ outv2,
               int M, int N, int K, int lda, int ldb,
               const float* __restrict__ xg, const float* __restrict__ og,
               const float* __restrict__ seg, const int* __restrict__ stepp)
{
    constexpr int NT  = TN / 32;
    constexpr int NBP = TN / 64;
    constexpr int R   = (TN == 64) ? 4 : 3;
    __shared__ bf16 As[R][128 * 32];
    __shared__ bf16 Bs[R][TN * 32];
    const int tid  = threadIdx.x;
    const int lane = tid & 63;
    const int w    = tid >> 6;
    const int wm   = w & 1, wn = w >> 1;
    const int fr   = lane & 15;
    const int q    = lane >> 4;

    if (SPLITK) {
        int z = blockIdx.z;
        A  += (size_t)z * K;
        Bt += (size_t)z * K;
    }

    const int tn_g = gridDim.x;
    const int nwg  = tn_g * gridDim.y;
    const int bid  = blockIdx.y * tn_g + blockIdx.x;
    const int o    = (bid & 7) * (nwg >> 3) + (bid >> 3);
    const int bandw = 8 * tn_g;
    const int band  = o / bandw;
    const int rr    = o - band * bandw;
    const int row0 = (band * 8 + (rr & 7)) * 128;
    const int col0 = (rr >> 3) * TN;

    const bf16* gA[2]; int sA_[2];
    #pragma unroll
    for (int p = 0; p < 2; ++p) {
        int s  = p * 256 + tid;
        int m  = s >> 2;
        int qg = (s & 3) ^ ((m >> 1) & 3);
        gA[p]  = A + (size_t)(row0 + m) * lda + qg * 8;
        sA_[p] = s * 8;
    }
    const bf16* gB[NBP]; int sB_[NBP];
    #pragma unroll
    for (int p = 0; p < NBP; ++p) {
        int s  = p * 256 + tid;
        int m  = s >> 2;
        int qg = (s & 3) ^ ((m >> 1) & 3);
        gB[p]  = Bt + (size_t)(col0 + m) * ldb + qg * 8;
        sB_[p] = s * 8;
    }

    int aoff[4], boff[NT];
    #pragma unroll
    for (int t = 0; t < 4; ++t) {
        int ml  = wm * 64 + t * 16 + fr;
        aoff[t] = (ml * 4 + (q ^ ((ml >> 1) & 3))) * 8;
    }
    #pragma unroll
    for (int t = 0; t < NT; ++t) {
        int nl  = wn * (TN / 2) + t * 16 + fr;
        boff[t] = (nl * 4 + (q ^ ((nl >> 1) & 3))) * 8;
    }

    #pragma unroll
    for (int pt = 0; pt < R - 1; ++pt) {
        #pragma unroll
        for (int p = 0; p < 2; ++p)   gload_lds16(gA[p] + pt * 32, &As[pt][sA_[p]]);
        #pragma unroll
        for (int p = 0; p < NBP; ++p) gload_lds16(gB[p] + pt * 32, &Bs[pt][sB_[p]]);
    }

    floatx4 acc[4][NT] = {};
    const int nk = K >> 5;
    int cur = 0;
    int kst = (R - 1) * 32;

    for (int t = 0; t < nk; ++t) {
        if constexpr (TN == 64) asm volatile("s_waitcnt vmcnt(6)" ::: "memory");
        else                    asm volatile("s_waitcnt vmcnt(4)" ::: "memory");
        __builtin_amdgcn_s_barrier();
        asm volatile("" ::: "memory");

        if (kst < K) {
            int sb = (cur == 0) ? (R - 1) : (cur - 1);
            #pragma unroll
            for (int p = 0; p < 2; ++p)   gload_lds16(gA[p] + kst, &As[sb][sA_[p]]);
            #pragma unroll
            for (int p = 0; p < NBP; ++p) gload_lds16(gB[p] + kst, &Bs[sb][sB_[p]]);
            kst += 32;
        }

        short8 af[4], bfg[NT];
        #pragma unroll
        for (int i = 0; i < 4; ++i)  af[i]  = *(const short8*)(&As[cur][aoff[i]]);
        #pragma unroll
        for (int j = 0; j < NT; ++j) bfg[j] = *(const short8*)(&Bs[cur][boff[j]]);
        #pragma unroll
        for (int i = 0; i < 4; ++i)
            #pragma unroll
            for (int j = 0; j < NT; ++j)
                acc[i][j] = __builtin_amdgcn_mfma_f32_16x16x32_bf16(af[i], bfg[j], acc[i][j], 0, 0, 0);

        cur = (cur == R - 1) ? 0 : (cur + 1);
    }

    void* outp = outv;
    float bscale = 1.0f;
    if (SPLITK && blockIdx.z != 0) { outp = outv2; bscale = 0.0f; }

    int st = 0;
    if (EPI == 3) {
        st = stepp[0];
        st = st < 0 ? 0 : (st > MAXSTEPS - 1 ? MAXSTEPS - 1 : st);
    }

    float bv[NT], sv[NT];
    #pragma unroll
    for (int nt = 0; nt < NT; ++nt) {
        int col = col0 + wn * (TN / 2) + nt * 16 + fr;
        bv[nt] = bias[col] * bscale;
        if (EPI == 3) sv[nt] = seg[st * D_MODEL + col];
    }
    #pragma unroll
    for (int mt = 0; mt < 4; ++mt) {
        #pragma unroll
        for (int nt = 0; nt < NT; ++nt) {
            int col = col0 + wn * (TN / 2) + nt * 16 + fr;
            #pragma unroll
            for (int r = 0; r < 4; ++r) {
                int row = row0 + wm * 64 + mt * 16 + q * 4 + r;
                float v = acc[mt][nt][r] + bv[nt];
                if (EPI == 0) {
                    ((float*)outp)[(size_t)row * N + col] = v;
                } else if (EPI == 1) {
                    ((bf16*)outp)[(size_t)row * N + col] = f2b(v);
                } else {
                    float g = 1.0f / (1.0f + __expf(-v));
                    size_t idx = (size_t)row * N + col;
                    float mix = xg[idx] * (1.0f - g) + og[idx] * g + sv[nt];
                    ((bf16*)outp)[idx] = f2b(mix);
                }
            }
        }
    }
}

// ---------------------------------------------------------------------------
// gemm_areg: 256x128 block tile, 4 waves of 128x64, **A direct-to-register**
// (no LDS for A). R18 rationale: at 2380 cy/k-step the aggregate LDS pipe
// (DMA-write 24KB + dup reads 48KB per block-k-step) is the largest term
// (~1100-1700 cy/CU-k-step) vs the ~1040 cy MFMA floor — invariant across
// all schedules tried (R9/R11/R12). A-frags load straight from global
// (16B/lane, 64B x 16-row segments, L2-resident), 1-tile register prefetch
// (af0/af1 rotation, static names per rule #20). B keeps the proven
// global_load_lds R=3 ring. LDS traffic 72KB -> 24KB per block-k-step.
// Per sub-iter: issue A(t+1) [8], issue B-stage(t+2) [2], ds_read B(t) +
// 32 MFMA, vmcnt(2) [retires A(t+1)+B(t+1): B(t+1) is >=10 slots older],
// barrier. Compiler's own dependency waits additionally protect af regs.
// No R16-style hazard: no ds_write chains on any load.
// Requires nk even (K=1024 here). EPI: 1 = bf16, 2 = exact-GELU bf16.
// ---------------------------------------------------------------------------
template<int EPI>
__global__ __launch_bounds__(256, 2)
void gemm_areg(const bf16* __restrict__ A, const bf16* __restrict__ Bt,
               const float* __restrict__ bias, bf16* __restrict__ out,
               int M, int N, int K)
{
    __shared__ bf16 Bs[3][128 * 32];
    const int tid  = threadIdx.x;
    const int lane = tid & 63;
    const int w    = tid >> 6;
    const int wm   = w & 1, wn = w >> 1;
    const int fr   = lane & 15;
    const int q    = lane >> 4;

    const int tn_g = gridDim.x;
    const int nwg  = tn_g * gridDim.y;
    const int bid  = blockIdx.y * tn_g + blockIdx.x;
    const int o    = (bid & 7) * (nwg >> 3) + (bid >> 3);
    const int bandw = 8 * tn_g;
    const int band  = o / bandw;
    const int rr    = o - band * bandw;
    const int row0 = (band * 8 + (rr & 7)) * 256;
    const int col0 = (rr >> 3) * 128;

    // per-lane A fragment pointers (8 m-frags; 16B each at col q*8)
    const bf16* gAf[8];
    #pragma unroll
    for (int i = 0; i < 8; ++i)
        gAf[i] = A + (size_t)(row0 + wm * 128 + i * 16 + fr) * K + q * 8;

    // B staging (2 chunks/thread), XOR pre-swizzled source (unchanged)
    const bf16* gB[2]; int sB_[2];
    #pragma unroll
    for (int p = 0; p < 2; ++p) {
        int s  = p * 256 + tid;
        int m  = s >> 2;
        int qg = (s & 3) ^ ((m >> 1) & 3);
        gB[p]  = Bt + (size_t)(col0 + m) * K + qg * 8;
        sB_[p] = s * 8;
    }
    int boff[4];
    #pragma unroll
    for (int t = 0; t < 4; ++t) {
        int nl  = wn * 64 + t * 16 + fr;
        boff[t] = (nl * 4 + (q ^ ((nl >> 1) & 3))) * 8;
    }

#define STAGE_B(TAU, BUF)                                                     \
    { _Pragma("unroll")                                                       \
      for (int p = 0; p < 2; ++p)                                             \
          gload_lds16(gB[p] + (TAU) * 32, &Bs[BUF][sB_[p]]); }

    short8 af0[8], af1[8];

    // prologue: A(0) -> af0 first, then B(0),B(1); vmcnt(2) retires A0+B0
    // (leaves B1 in flight) regardless of intra-block ordering.
    #pragma unroll
    for (int i = 0; i < 8; ++i) af0[i] = *(const short8*)(gAf[i]);
    STAGE_B(0, 0);
    STAGE_B(1, 1);
    asm volatile("s_waitcnt vmcnt(2)" ::: "memory");
    __builtin_amdgcn_s_barrier();
    asm volatile("" ::: "memory");

    floatx4 acc[8][4] = {};
    const int nk = K >> 5;   // must be even
    int bcur = 0;

    for (int t = 0; t < nk; t += 2) {
        int bn1 = (bcur == 2) ? 0 : bcur + 1;      // buf of tile t+1
        int bn2 = (bn1  == 2) ? 0 : bn1 + 1;       // buf of tile t+2
        // ---- sub-iter even: compute tile t (af0), prefetch A(t+1), B(t+2)
        if (t + 1 < nk) {
            int k1 = (t + 1) << 5;
            #pragma unroll
            for (int i = 0; i < 8; ++i) af1[i] = *(const short8*)(gAf[i] + k1);
        }
        if (t + 2 < nk) STAGE_B(t + 2, bn2);
        {
            short8 bfg[4];
            #pragma unroll
            for (int j = 0; j < 4; ++j) bfg[j] = *(const short8*)(&Bs[bcur][boff[j]]);
            __builtin_amdgcn_s_setprio(1);
            #pragma unroll
            for (int i = 0; i < 8; ++i)
                #pragma unroll
                for (int j = 0; j < 4; ++j)
                    acc[i][j] = __builtin_amdgcn_mfma_f32_16x16x32_bf16(af0[i], bfg[j], acc[i][j], 0, 0, 0);
            __builtin_amdgcn_s_setprio(0);
        }
        asm volatile("s_waitcnt vmcnt(2)" ::: "memory");
        __builtin_amdgcn_s_barrier();
        asm volatile("" ::: "memory");

        // ---- sub-iter odd: compute tile t+1 (af1), prefetch A(t+2), B(t+3)
        if (t + 2 < nk) {
            int k2 = (t + 2) << 5;
            #pragma unroll
            for (int i = 0; i < 8; ++i) af0[i] = *(const short8*)(gAf[i] + k2);
        }
        if (t + 3 < nk) STAGE_B(t + 3, bcur);      // buf of t+3 = bcur
        {
            short8 bfg[4];
            #pragma unroll
            for (int j = 0; j < 4; ++j) bfg[j] = *(const short8*)(&Bs[bn1][boff[j]]);
            __builtin_amdgcn_s_setprio(1);
            #pragma unroll
            for (int i = 0; i < 8; ++i)
                #pragma unroll
                for (int j = 0; j < 4; ++j)
                    acc[i][j] = __builtin_amdgcn_mfma_f32_16x16x32_bf16(af1[i], bfg[j], acc[i][j], 0, 0, 0);
            __builtin_amdgcn_s_setprio(0);
        }
        asm volatile("s_waitcnt vmcnt(2)" ::: "memory");
        __builtin_amdgcn_s_barrier();
        asm volatile("" ::: "memory");

        bcur = bn2;
    }
#undef STAGE_B

    float bv[4];
    #pragma unroll
    for (int j = 0; j < 4; ++j) bv[j] = bias[col0 + wn * 64 + j * 16 + fr];
    #pragma unroll
    for (int mt = 0; mt < 8; ++mt) {
        #pragma unroll
        for (int nt = 0; nt < 4; ++nt) {
            int col = col0 + wn * 64 + nt * 16 + fr;
            #pragma unroll
            for (int r = 0; r < 4; ++r) {
                int row = row0 + wm * 128 + mt * 16 + q * 4 + r;
                float v = acc[mt][nt][r] + bv[nt];
                if (EPI == 1) {
                    out[(size_t)row * N + col] = f2b(v);
                } else {
                    float g = 0.5f * v * (1.0f + erff(v * 0.70710678118654752f));
                    out[(size_t)row * N + col] = f2b(g);
                }
            }
        }
    }
}

// ---------------------------------------------------------------------------
// Batched weight transpose-convert: all 5 weights in ONE launch.
// Tile counts: Wg 2048 | Wqkv 3072 | Wout 1024 | W1 4096 | W2 4096 = 14336.
// ---------------------------------------------------------------------------
#define NTRANS_BLOCKS 14336
__global__ __launch_bounds__(256)
void transpose_all_kernel(const float* __restrict__ Wg,   bf16* __restrict__ WgT,
                          const float* __restrict__ Wqkv, bf16* __restrict__ WqkvT,
                          const float* __restrict__ Wout, bf16* __restrict__ WoutT,
                          const float* __restrict__ W1,   bf16* __restrict__ W1T,
                          const float* __restrict__ W2,   bf16* __restrict__ W2T)
{
    __shared__ float t[32][33];
    const int bid = blockIdx.x;
    if (bid >= NTRANS_BLOCKS) return;
    const float* W; bf16* WT; int K, N, base;
    if      (bid <  2048) { W = Wg;   WT = WgT;   K = 2048; N = 1024; base = 0; }
    else if (bid <  5120) { W = Wqkv; WT = WqkvT; K = 1024; N = 3072; base = 2048; }
    else if (bid <  6144) { W = Wout; WT = WoutT; K = 1024; N = 1024; base = 5120; }
    else if (bid < 10240) { W = W1;   WT = W1T;   K = 1024; N = 4096; base = 6144; }
    else                  { W = W2;   WT = W2T;   K = 4096; N = 1024; base = 10240; }
    const int lb  = bid - base;
    const int ntx = N >> 5;
    const int n0 = (lb % ntx) * 32, k0 = (lb / ntx) * 32;
    const int tx = threadIdx.x & 31, ty = threadIdx.x >> 5;
    #pragma unroll
    for (int i = 0; i < 4; ++i)
        t[ty + i * 8][tx] = W[(size_t)(k0 + ty + i * 8) * N + n0 + tx];
    __syncthreads();
    #pragma unroll
    for (int i = 0; i < 4; ++i)
        WT[(size_t)(n0 + ty + i * 8) * K + k0 + tx] = f2b(t[tx][ty + i * 8]);
}

// ---------------------------------------------------------------------------
// xcat: build [x|orig] bf16 (T,2048)
// ---------------------------------------------------------------------------
__global__ __launch_bounds__(256)
void xcat_kernel(const float* __restrict__ x, const float* __restrict__ orig,
                 bf16* __restrict__ xcat)
{
    int i = blockIdx.x * 256 + threadIdx.x;
    float4 xv = ((const float4*)x)[i];
    float4 ov = ((const float4*)orig)[i];
    int t = i >> 8, c4 = (i & 255) * 4;
    bf16* px = xcat + (size_t)t * 2048 + c4;
    px[0] = f2b(xv.x); px[1] = f2b(xv.y); px[2] = f2b(xv.z); px[3] = f2b(xv.w);
    bf16* po = px + 1024;
    po[0] = f2b(ov.x); po[1] = f2b(ov.y); po[2] = f2b(ov.z); po[3] = f2b(ov.w);
}

// ---------------------------------------------------------------------------
// V transpose: qkv (T,3072) v-part -> Vt (B,H,64,S) bf16
// ---------------------------------------------------------------------------
__global__ __launch_bounds__(256)
void vtrans_kernel(const bf16* __restrict__ qkv, bf16* __restrict__ Vt)
{
    __shared__ float t[32][33];
    const int blk = blockIdx.x;
    const int dt = blk & 1;
    const int st = (blk >> 1) & 31;
    const int h  = (blk >> 6) & 15;
    const int b  = blk >> 10;
    const int tx = threadIdx.x & 31, ty = threadIdx.x >> 5;
    #pragma unroll
    for (int i = 0; i < 4; ++i)
        t[ty + i * 8][tx] = b2f(qkv[(size_t)(b * SEQ + st * 32 + ty + i * 8) * 3072
                                    + 2048 + h * 64 + dt * 32 + tx]);
    __syncthreads();
    #pragma unroll
    for (int i = 0; i < 4; ++i)
        Vt[(size_t)((b * NH + h) * 64 + dt * 32 + ty + i * 8) * SEQ + st * 32 + tx]
            = f2b(t[tx][ty + i * 8]);
}

// ---------------------------------------------------------------------------
// MFMA flash attention (R10: static-max softmax, __expf, LDS relb, setprio).
// ---------------------------------------------------------------------------
__global__ __launch_bounds__(256)
void fattn_kernel(const bf16* __restrict__ qkv, const bf16* __restrict__ Vt,
                  const float* __restrict__ relb, bf16* __restrict__ out)
{
    __shared__ bf16 KPs[128 * 64];
    __shared__ bf16 Vs [64 * 128];
    __shared__ float relb_s[1088];

    const int tid  = threadIdx.x;
    const int lane = tid & 63;
    const int w    = tid >> 6;
    const int fr   = lane & 15;
    const int quad = lane >> 4;

    const int qt = blockIdx.x & 15;
    const int h  = (blockIdx.x >> 4) & 15;
    const int b  = blockIdx.x >> 8;
    const int bq = b * SEQ;
    const int bh = b * NH + h;

    for (int i = tid; i < 1087; i += 256)
        relb_s[i] = relb[qt * 64 + i] - 8.0f;

    const int qrow = bq + qt * 64 + w * 16 + fr;
    short8 qf[2];
    {
        const bf16* qp = qkv + (size_t)qrow * 3072 + h * 64 + quad * 8;
        qf[0] = *(const short8*)(qp);
        qf[1] = *(const short8*)(qp + 32);
    }

    int ibase[4];
    #pragma unroll
    for (int r = 0; r < 4; ++r)
        ibase[r] = (w * 16 + quad * 4 + r) - fr + 1023;

    float lsum[4] = {0.f, 0.f, 0.f, 0.f};
    floatx4 accO[4];
    #pragma unroll
    for (int nt = 0; nt < 4; ++nt) accO[nt] = (floatx4){0.f, 0.f, 0.f, 0.f};

    for (int k0 = 0; k0 < SEQ; k0 += 128) {
        __syncthreads();
        #pragma unroll
        for (int it = 0; it < 4; ++it) {
            int s = it * 256 + tid;
            int key = s >> 3, cs = s & 7;
            int c = cs ^ (key & 7);
            const bf16* src = qkv + (size_t)(bq + k0 + key) * 3072 + 1024 + h * 64 + c * 8;
            gload_lds16(src, KPs + (size_t)s * 8);
        }
        #pragma unroll
        for (int it = 0; it < 4; ++it) {
            int s = it * 256 + tid;
            int row = s >> 4, cs = s & 15;
            int c = cs ^ (row & 15);
            const bf16* src = Vt + (size_t)(bh * 64 + row) * SEQ + k0 + c * 8;
            gload_lds16(src, Vs + (size_t)s * 8);
        }
        __syncthreads();

        floatx4 accS[8];
        #pragma unroll
        for (int t = 0; t < 8; ++t) accS[t] = (floatx4){0.f, 0.f, 0.f, 0.f};
        __builtin_amdgcn_s_setprio(1);
        #pragma unroll
        for (int t = 0; t < 8; ++t) {
            int row = t * 16 + fr;
            #pragma unroll
            for (int ks = 0; ks < 2; ++ks) {
                int slot = (ks * 4 + quad) ^ (row & 7);
                short8 kf = *(const short8*)(KPs + (size_t)row * 64 + slot * 8);
                accS[t] = __builtin_amdgcn_mfma_f32_16x16x32_bf16(qf[ks], kf, accS[t], 0, 0, 0);
            }
        }
        __builtin_amdgcn_s_setprio(0);

        __syncthreads();

        bf16* Ps = KPs + w * 2048;
        #pragma unroll
        for (int t = 0; t < 8; ++t) {
            int keyl = t * 16 + fr;
            int cbase = keyl >> 3, koff = keyl & 7;
            #pragma unroll
            for (int r = 0; r < 4; ++r) {
                float bias = relb_s[ibase[r] - k0 - t * 16];
                float p = __expf(fmaf(accS[t][r], 0.125f, bias));
                lsum[r] += p;
                int row = quad * 4 + r;
                int slot = cbase ^ (row & 15);
                Ps[(size_t)row * 128 + slot * 8 + koff] = f2b(p);
            }
        }

        __builtin_amdgcn_s_setprio(1);
        #pragma unroll
        for (int ks = 0; ks < 4; ++ks) {
            int slotp = (ks * 4 + quad) ^ (fr & 15);
            short8 pf = *(const short8*)(Ps + (size_t)fr * 128 + slotp * 8);
            #pragma unroll
            for (int nt = 0; nt < 4; ++nt) {
                int vrow = nt * 16 + fr;
                int slotv = (ks * 4 + quad) ^ (vrow & 15);
                short8 vf = *(const short8*)(Vs + (size_t)vrow * 128 + slotv * 8);
                accO[nt] = __builtin_amdgcn_mfma_f32_16x16x32_bf16(pf, vf, accO[nt], 0, 0, 0);
            }
        }
        __builtin_amdgcn_s_setprio(0);
    }

    float inv[4];
    #pragma unroll
    for (int r = 0; r < 4; ++r) {
        float v = lsum[r];
        v += __shfl_xor(v, 1); v += __shfl_xor(v, 2);
        v += __shfl_xor(v, 4); v += __shfl_xor(v, 8);
        inv[r] = 1.0f / v;
    }

    #pragma unroll
    for (int nt = 0; nt < 4; ++nt) {
        int col = h * 64 + nt * 16 + fr;
        #pragma unroll
        for (int r = 0; r < 4; ++r) {
            int t = bq + qt * 64 + w * 16 + quad * 4 + r;
            out[(size_t)t * D_MODEL + col] = f2b(accO[nt][r] * inv[r]);
        }
    }
}

// ---------------------------------------------------------------------------
// Fused residual + LayerNorm (optionally sums TWO fp32 add-terms: split-K)
// ---------------------------------------------------------------------------
template<bool OUT_BF16, bool HAS2>
__global__ __launch_bounds__(256)
void ln_kernel(const bf16* __restrict__ a, const float* __restrict__ add,
               const float* __restrict__ add2,
               const float* __restrict__ g, const float* __restrict__ bb,
               void* __restrict__ outv)
{
    __shared__ float red[256];
    __shared__ float red2[256];
    const int row = blockIdx.x;
    const int tid = threadIdx.x;
    float s[4];
    float lsum = 0.f, lsq = 0.f;
    #pragma unroll
    for (int u = 0; u < 4; ++u) {
        int i = tid + 256 * u;
        float v = b2f(a[row * D_MODEL + i]) + add[row * D_MODEL + i];
        if (HAS2) v += add2[row * D_MODEL + i];
        s[u] = v; lsum += v; lsq += v * v;
    }
    red[tid] = lsum; red2[tid] = lsq; __syncthreads();
    for (int s2 = 128; s2 > 0; s2 >>= 1) {
        if (tid < s2) { red[tid] += red[tid + s2]; red2[tid] += red2[tid + s2]; }
        __syncthreads();
    }
    float mean = red[0] * (1.0f / D_MODEL);
    float var  = red2[0] * (1.0f / D_MODEL) - mean * mean;
    float rs = rsqrtf(var + 1e-5f);
    #pragma unroll
    for (int u = 0; u < 4; ++u) {
        int i = tid + 256 * u;
        float o = (s[u] - mean) * rs * g[i] + bb[i];
        if (OUT_BF16) ((bf16*)outv)[row * D_MODEL + i] = f2b(o);
        else          ((float*)outv)[row * D_MODEL + i] = o;
    }
}

// ---------------------------------------------------------------------------
extern "C" void kernel_launch(void* const* d_in, const int* in_sizes, int n_in,
                              void* d_out, int out_size, void* d_ws, size_t ws_size,
                              hipStream_t stream)
{
    const float* x     = (const float*)d_in[0];
    const float* orig  = (const float*)d_in[1];
    const int*   step  = (const int*)  d_in[2];
    const float* se    = (const float*)d_in[3];
    const float* Wqkv  = (const float*)d_in[4];
    const float* bqkv  = (const float*)d_in[5];
    const float* Wout  = (const float*)d_in[6];
    const float* bout  = (const float*)d_in[7];
    const float* Wg    = (const float*)d_in[8];
    const float* bg    = (const float*)d_in[9];
    const float* relb  = (const float*)d_in[10];
    const float* W1    = (const float*)d_in[11];
    const float* b1    = (const float*)d_in[12];
    const float* W2    = (const float*)d_in[13];
    const float* b2    = (const float*)d_in[14];
    const float* ln1g  = (const float*)d_in[15];
    const float* ln1b  = (const float*)d_in[16];
    const float* ln2g  = (const float*)d_in[17];
    const float* ln2b  = (const float*)d_in[18];

    // Workspace layout (76 MB) — lifetimes verified against kernel timeline:
    //   0-4   WgT   (r: gate)          | tmp2 0-16 (w: FFN-down, r: LN2)
    //   4-10  WqkvT (r: QKV)           |   -> all those regions dead by then
    //   10-12 WoutT (r: Wout-proj)
    //   12-20 W1T   (r: FFN-up)
    //   20-28 W2T   (r: FFN-down; NOT overlapped by tmp2)
    //   28-36 xw    (w: gate-epi; rw: LN1; r: QKV, FFN-up, LN2)
    //   36-52 xcat  (w: xcat; r: gate)  | attnb 36-44 (w: fattn, r: Wout)
    //   44-76 h     (w: FFN-up, r: FFN-down; overlaps qkvb after its last read)
    //   52-76 qkvb  (w: QKV; r: vtrans, fattn)
    //   Vt = d_out  (w: vtrans, r: fattn; then tmp from Wout on)
    char* ws = (char*)d_ws;
    bf16* WgT   = (bf16*)(ws);
    bf16* WqkvT = (bf16*)(ws + ( 4u << 20));
    bf16* WoutT = (bf16*)(ws + (10u << 20));
    bf16* W1T   = (bf16*)(ws + (12u << 20));
    bf16* W2T   = (bf16*)(ws + (20u << 20));
    bf16* xw    = (bf16*)(ws + (28u << 20));
    bf16* xcat  = (bf16*)(ws + (36u << 20));
    bf16* attnb = (bf16*)(ws + (36u << 20));
    bf16* h     = (bf16*)(ws + (44u << 20));
    bf16* qkvb  = (bf16*)(ws + (52u << 20));
    float* tmp2 = (float*)(ws);
    bf16* Vt    = (bf16*)d_out;
    float* tmp  = (float*)d_out;

    dim3 blk(256);

    // 0. all weight transposes in one launch + xcat build
    transpose_all_kernel<<<NTRANS_BLOCKS, blk, 0, stream>>>(Wg, WgT, Wqkv, WqkvT,
                                                    Wout, WoutT, W1, W1T, W2, W2T);
    xcat_kernel<<<TOK, blk, 0, stream>>>(x, orig, xcat);

    // 1. gate GEMM (A = xcat via async LDS-DMA) + gatemix epilogue -> xw
    mfma_gemm<64, 3, false><<<dim3(D_MODEL/64, TOK/128), blk, 0, stream>>>(
        xcat, WgT, bg, xw, nullptr, TOK, D_MODEL, 2*D_MODEL, 2*D_MODEL, 2*D_MODEL,
        x, orig, se, step);

    // 2. QKV projection -> qkvb   [A-in-reg 256x128, grid 24x16]
    gemm_areg<1><<<dim3(3*D_MODEL/128, TOK/256), blk, 0, stream>>>(
        xw, WqkvT, bqkv, qkvb, TOK, 3*D_MODEL, D_MODEL);

    // 3a. V transpose -> Vt (= d_out scratch)
    vtrans_kernel<<<BATCH*NH*64, blk, 0, stream>>>(qkvb, Vt);

    // 3b. MFMA flash attention -> attnb
    fattn_kernel<<<BATCH*NH*(SEQ/64), blk, 0, stream>>>(qkvb, Vt, relb, attnb);

    // 4. output projection -> tmp (fp32, overwrites Vt scratch)
    mfma_gemm<64, 0, false><<<dim3(D_MODEL/64, TOK/128), blk, 0, stream>>>(
        attnb, WoutT, bout, tmp, nullptr, TOK, D_MODEL, D_MODEL, D_MODEL, D_MODEL,
        nullptr, nullptr, nullptr, nullptr);

    // 5. LN1(xw + tmp) -> xw (bf16, in place)
    ln_kernel<true, false><<<TOK, blk, 0, stream>>>(xw, tmp, nullptr, ln1g, ln1b, xw);

    // 6. FFN up + exact GELU -> h   [A-in-reg 256x128, grid 32x16]
    gemm_areg<2><<<dim3(DFF/128, TOK/256), blk, 0, stream>>>(
        xw, W1T, b1, h, TOK, DFF, D_MODEL);

    // 7. FFN down, split-K=2, TN=128 -> tmp (z=0) + tmp2 (z=1)
    mfma_gemm<128, 0, true><<<dim3(D_MODEL/128, TOK/128, 2), blk, 0, stream>>>(
        h, W2T, b2, tmp, tmp2, TOK, D_MODEL, DFF/2, DFF, DFF,
        nullptr, nullptr, nullptr, nullptr);

    // 8. LN2(xw + tmp + tmp2) -> d_out (fp32, in place over tmp)
    ln_kernel<false, true><<<TOK, blk, 0, stream>>>(xw, tmp, tmp2, ln2g, ln2b, d_out);
}

// Round 12
// 428.325 us; speedup vs baseline: 1.1502x; 1.1502x over previous
//
#include <hip/hip_runtime.h>
#include <hip/hip_bf16.h>
#include <math.h>

#define D_MODEL 1024
#define NH      16
#define HD      64
#define DFF     4096
#define SEQ     1024
#define BATCH   4
#define TOK     (BATCH*SEQ)   // 4096 tokens
#define MAXSTEPS 24

typedef __hip_bfloat16 bf16;
typedef __attribute__((ext_vector_type(8))) short short8;   // 8 bf16 = one MFMA frag
typedef __attribute__((ext_vector_type(4))) float floatx4;  // MFMA acc

__device__ __forceinline__ float b2f(bf16 v){ return __bfloat162float(v); }
__device__ __forceinline__ bf16  f2b(float v){ return __float2bfloat16(v); }

__device__ __forceinline__ void gload_lds16(const bf16* g, bf16* l){
    __builtin_amdgcn_global_load_lds((const __attribute__((address_space(1))) void*)g,
                                     (__attribute__((address_space(3))) void*)l, 16, 0, 0);
}

// ---------------------------------------------------------------------------
// mfma_gemm: C = A[M,*](bf16,lda) * Bt[N,*]^T(bf16,ldb) + bias.
// 128 x TN tile, 4 waves 2x2 (wave 64 x TN/2). R12 ring pipeline
// (R-deep LDS ring via global_load_lds, counted vmcnt, 1 barrier/k-step).
// R18 lesson: A direct-to-register loses (poor 64B-segment coalescing +
// vmcnt miscount drains just-issued loads). gload_lds ring is the path.
// EPI: 0 fp32 | 1 bf16 | 3 gatemix (sigmoid + step-embed, reads x/orig).
// ---------------------------------------------------------------------------
template<int TN, int EPI, bool SPLITK>
__global__ __launch_bounds__(256)
void mfma_gemm(const bf16* __restrict__ A, const bf16* __restrict__ Bt,
               const float* __restrict__ bias, void* __restrict__ outv,
               void* __restrict__ outv2,
               int M, int N, int K, int lda, int ldb,
               const float* __restrict__ xg, const float* __restrict__ og,
               const float* __restrict__ seg, const int* __restrict__ stepp)
{
    constexpr int NT  = TN / 32;
    constexpr int NBP = TN / 64;
    constexpr int R   = (TN == 64) ? 4 : 3;
    __shared__ bf16 As[R][128 * 32];
    __shared__ bf16 Bs[R][TN * 32];
    const int tid  = threadIdx.x;
    const int lane = tid & 63;
    const int w    = tid >> 6;
    const int wm   = w & 1, wn = w >> 1;
    const int fr   = lane & 15;
    const int q    = lane >> 4;

    if (SPLITK) {
        int z = blockIdx.z;
        A  += (size_t)z * K;
        Bt += (size_t)z * K;
    }

    const int tn_g = gridDim.x;
    const int nwg  = tn_g * gridDim.y;
    const int bid  = blockIdx.y * tn_g + blockIdx.x;
    const int o    = (bid & 7) * (nwg >> 3) + (bid >> 3);
    const int bandw = 8 * tn_g;
    const int band  = o / bandw;
    const int rr    = o - band * bandw;
    const int row0 = (band * 8 + (rr & 7)) * 128;
    const int col0 = (rr >> 3) * TN;

    const bf16* gA[2]; int sA_[2];
    #pragma unroll
    for (int p = 0; p < 2; ++p) {
        int s  = p * 256 + tid;
        int m  = s >> 2;
        int qg = (s & 3) ^ ((m >> 1) & 3);
        gA[p]  = A + (size_t)(row0 + m) * lda + qg * 8;
        sA_[p] = s * 8;
    }
    const bf16* gB[NBP]; int sB_[NBP];
    #pragma unroll
    for (int p = 0; p < NBP; ++p) {
        int s  = p * 256 + tid;
        int m  = s >> 2;
        int qg = (s & 3) ^ ((m >> 1) & 3);
        gB[p]  = Bt + (size_t)(col0 + m) * ldb + qg * 8;
        sB_[p] = s * 8;
    }

    int aoff[4], boff[NT];
    #pragma unroll
    for (int t = 0; t < 4; ++t) {
        int ml  = wm * 64 + t * 16 + fr;
        aoff[t] = (ml * 4 + (q ^ ((ml >> 1) & 3))) * 8;
    }
    #pragma unroll
    for (int t = 0; t < NT; ++t) {
        int nl  = wn * (TN / 2) + t * 16 + fr;
        boff[t] = (nl * 4 + (q ^ ((nl >> 1) & 3))) * 8;
    }

    #pragma unroll
    for (int pt = 0; pt < R - 1; ++pt) {
        #pragma unroll
        for (int p = 0; p < 2; ++p)   gload_lds16(gA[p] + pt * 32, &As[pt][sA_[p]]);
        #pragma unroll
        for (int p = 0; p < NBP; ++p) gload_lds16(gB[p] + pt * 32, &Bs[pt][sB_[p]]);
    }

    floatx4 acc[4][NT] = {};
    const int nk = K >> 5;
    int cur = 0;
    int kst = (R - 1) * 32;

    for (int t = 0; t < nk; ++t) {
        if constexpr (TN == 64) asm volatile("s_waitcnt vmcnt(6)" ::: "memory");
        else                    asm volatile("s_waitcnt vmcnt(4)" ::: "memory");
        __builtin_amdgcn_s_barrier();
        asm volatile("" ::: "memory");

        if (kst < K) {
            int sb = (cur == 0) ? (R - 1) : (cur - 1);
            #pragma unroll
            for (int p = 0; p < 2; ++p)   gload_lds16(gA[p] + kst, &As[sb][sA_[p]]);
            #pragma unroll
            for (int p = 0; p < NBP; ++p) gload_lds16(gB[p] + kst, &Bs[sb][sB_[p]]);
            kst += 32;
        }

        short8 af[4], bfg[NT];
        #pragma unroll
        for (int i = 0; i < 4; ++i)  af[i]  = *(const short8*)(&As[cur][aoff[i]]);
        #pragma unroll
        for (int j = 0; j < NT; ++j) bfg[j] = *(const short8*)(&Bs[cur][boff[j]]);
        #pragma unroll
        for (int i = 0; i < 4; ++i)
            #pragma unroll
            for (int j = 0; j < NT; ++j)
                acc[i][j] = __builtin_amdgcn_mfma_f32_16x16x32_bf16(af[i], bfg[j], acc[i][j], 0, 0, 0);

        cur = (cur == R - 1) ? 0 : (cur + 1);
    }

    void* outp = outv;
    float bscale = 1.0f;
    if (SPLITK && blockIdx.z != 0) { outp = outv2; bscale = 0.0f; }

    int st = 0;
    if (EPI == 3) {
        st = stepp[0];
        st = st < 0 ? 0 : (st > MAXSTEPS - 1 ? MAXSTEPS - 1 : st);
    }

    float bv[NT], sv[NT];
    #pragma unroll
    for (int nt = 0; nt < NT; ++nt) {
        int col = col0 + wn * (TN / 2) + nt * 16 + fr;
        bv[nt] = bias[col] * bscale;
        if (EPI == 3) sv[nt] = seg[st * D_MODEL + col];
    }
    #pragma unroll
    for (int mt = 0; mt < 4; ++mt) {
        #pragma unroll
        for (int nt = 0; nt < NT; ++nt) {
            int col = col0 + wn * (TN / 2) + nt * 16 + fr;
            #pragma unroll
            for (int r = 0; r < 4; ++r) {
                int row = row0 + wm * 64 + mt * 16 + q * 4 + r;
                float v = acc[mt][nt][r] + bv[nt];
                if (EPI == 0) {
                    ((float*)outp)[(size_t)row * N + col] = v;
                } else if (EPI == 1) {
                    ((bf16*)outp)[(size_t)row * N + col] = f2b(v);
                } else {
                    float g = 1.0f / (1.0f + __expf(-v));
                    size_t idx = (size_t)row * N + col;
                    float mix = xg[idx] * (1.0f - g) + og[idx] * g + sv[nt];
                    ((bf16*)outp)[idx] = f2b(mix);
                }
            }
        }
    }
}

// ---------------------------------------------------------------------------
// gemm_wide: 256x128 block tile, 4 waves of 128x64 (FLOP/LDS-byte 42.7 vs 32;
// R15-measured: FFN-up 74.5 -> 62 us). R=3 ring, vmcnt(6), LPT=6.
// LDS 72 KB -> 2 blocks/CU. EPI: 1 = bf16, 2 = exact-GELU bf16.
// ---------------------------------------------------------------------------
template<int EPI>
__global__ __launch_bounds__(256, 2)
void gemm_wide(const bf16* __restrict__ A, const bf16* __restrict__ Bt,
               const float* __restrict__ bias, bf16* __restrict__ out,
               int M, int N, int K)
{
    constexpr int R = 3;
    __shared__ bf16 As[R][256 * 32];
    __shared__ bf16 Bs[R][128 * 32];
    const int tid  = threadIdx.x;
    const int lane = tid & 63;
    const int w    = tid >> 6;
    const int wm   = w & 1, wn = w >> 1;
    const int fr   = lane & 15;
    const int q    = lane >> 4;

    const int tn_g = gridDim.x;
    const int nwg  = tn_g * gridDim.y;
    const int bid  = blockIdx.y * tn_g + blockIdx.x;
    const int o    = (bid & 7) * (nwg >> 3) + (bid >> 3);
    const int bandw = 8 * tn_g;
    const int band  = o / bandw;
    const int rr    = o - band * bandw;
    const int row0 = (band * 8 + (rr & 7)) * 256;
    const int col0 = (rr >> 3) * 128;

    const bf16* gA[4]; int sA_[4];
    #pragma unroll
    for (int p = 0; p < 4; ++p) {
        int s  = p * 256 + tid;
        int m  = s >> 2;
        int qg = (s & 3) ^ ((m >> 1) & 3);
        gA[p]  = A + (size_t)(row0 + m) * K + qg * 8;
        sA_[p] = s * 8;
    }
    const bf16* gB[2]; int sB_[2];
    #pragma unroll
    for (int p = 0; p < 2; ++p) {
        int s  = p * 256 + tid;
        int m  = s >> 2;
        int qg = (s & 3) ^ ((m >> 1) & 3);
        gB[p]  = Bt + (size_t)(col0 + m) * K + qg * 8;
        sB_[p] = s * 8;
    }

    int aoff[8], boff[4];
    #pragma unroll
    for (int t = 0; t < 8; ++t) {
        int ml  = wm * 128 + t * 16 + fr;
        aoff[t] = (ml * 4 + (q ^ ((ml >> 1) & 3))) * 8;
    }
    #pragma unroll
    for (int t = 0; t < 4; ++t) {
        int nl  = wn * 64 + t * 16 + fr;
        boff[t] = (nl * 4 + (q ^ ((nl >> 1) & 3))) * 8;
    }

    #pragma unroll
    for (int pt = 0; pt < R - 1; ++pt) {
        #pragma unroll
        for (int p = 0; p < 4; ++p) gload_lds16(gA[p] + pt * 32, &As[pt][sA_[p]]);
        #pragma unroll
        for (int p = 0; p < 2; ++p) gload_lds16(gB[p] + pt * 32, &Bs[pt][sB_[p]]);
    }

    floatx4 acc[8][4] = {};
    const int nk = K >> 5;
    int cur = 0;
    int kst = (R - 1) * 32;

    for (int t = 0; t < nk; ++t) {
        asm volatile("s_waitcnt vmcnt(6)" ::: "memory");
        __builtin_amdgcn_s_barrier();
        asm volatile("" ::: "memory");

        if (kst < K) {
            int sb = (cur == 0) ? (R - 1) : (cur - 1);
            #pragma unroll
            for (int p = 0; p < 4; ++p) gload_lds16(gA[p] + kst, &As[sb][sA_[p]]);
            #pragma unroll
            for (int p = 0; p < 2; ++p) gload_lds16(gB[p] + kst, &Bs[sb][sB_[p]]);
            kst += 32;
        }

        short8 af[8], bfg[4];
        #pragma unroll
        for (int i = 0; i < 8; ++i) af[i]  = *(const short8*)(&As[cur][aoff[i]]);
        #pragma unroll
        for (int j = 0; j < 4; ++j) bfg[j] = *(const short8*)(&Bs[cur][boff[j]]);
        __builtin_amdgcn_s_setprio(1);
        #pragma unroll
        for (int i = 0; i < 8; ++i)
            #pragma unroll
            for (int j = 0; j < 4; ++j)
                acc[i][j] = __builtin_amdgcn_mfma_f32_16x16x32_bf16(af[i], bfg[j], acc[i][j], 0, 0, 0);
        __builtin_amdgcn_s_setprio(0);

        cur = (cur == R - 1) ? 0 : (cur + 1);
    }

    float bv[4];
    #pragma unroll
    for (int j = 0; j < 4; ++j) bv[j] = bias[col0 + wn * 64 + j * 16 + fr];
    #pragma unroll
    for (int mt = 0; mt < 8; ++mt) {
        #pragma unroll
        for (int nt = 0; nt < 4; ++nt) {
            int col = col0 + wn * 64 + nt * 16 + fr;
            #pragma unroll
            for (int r = 0; r < 4; ++r) {
                int row = row0 + wm * 128 + mt * 16 + q * 4 + r;
                float v = acc[mt][nt][r] + bv[nt];
                if (EPI == 1) {
                    out[(size_t)row * N + col] = f2b(v);
                } else {
                    float g = 0.5f * v * (1.0f + erff(v * 0.70710678118654752f));
                    out[(size_t)row * N + col] = f2b(g);
                }
            }
        }
    }
}

// ---------------------------------------------------------------------------
// Batched weight transpose-convert: all 5 weights in ONE launch.
// Tile counts: Wg 2048 | Wqkv 3072 | Wout 1024 | W1 4096 | W2 4096 = 14336.
// ---------------------------------------------------------------------------
#define NTRANS_BLOCKS 14336
__global__ __launch_bounds__(256)
void transpose_all_kernel(const float* __restrict__ Wg,   bf16* __restrict__ WgT,
                          const float* __restrict__ Wqkv, bf16* __restrict__ WqkvT,
                          const float* __restrict__ Wout, bf16* __restrict__ WoutT,
                          const float* __restrict__ W1,   bf16* __restrict__ W1T,
                          const float* __restrict__ W2,   bf16* __restrict__ W2T)
{
    __shared__ float t[32][33];
    const int bid = blockIdx.x;
    if (bid >= NTRANS_BLOCKS) return;
    const float* W; bf16* WT; int K, N, base;
    if      (bid <  2048) { W = Wg;   WT = WgT;   K = 2048; N = 1024; base = 0; }
    else if (bid <  5120) { W = Wqkv; WT = WqkvT; K = 1024; N = 3072; base = 2048; }
    else if (bid <  6144) { W = Wout; WT = WoutT; K = 1024; N = 1024; base = 5120; }
    else if (bid < 10240) { W = W1;   WT = W1T;   K = 1024; N = 4096; base = 6144; }
    else                  { W = W2;   WT = W2T;   K = 4096; N = 1024; base = 10240; }
    const int lb  = bid - base;
    const int ntx = N >> 5;
    const int n0 = (lb % ntx) * 32, k0 = (lb / ntx) * 32;
    const int tx = threadIdx.x & 31, ty = threadIdx.x >> 5;
    #pragma unroll
    for (int i = 0; i < 4; ++i)
        t[ty + i * 8][tx] = W[(size_t)(k0 + ty + i * 8) * N + n0 + tx];
    __syncthreads();
    #pragma unroll
    for (int i = 0; i < 4; ++i)
        WT[(size_t)(n0 + ty + i * 8) * K + k0 + tx] = f2b(t[tx][ty + i * 8]);
}

// ---------------------------------------------------------------------------
// xcat: build [x|orig] bf16 (T,2048)
// ---------------------------------------------------------------------------
__global__ __launch_bounds__(256)
void xcat_kernel(const float* __restrict__ x, const float* __restrict__ orig,
                 bf16* __restrict__ xcat)
{
    int i = blockIdx.x * 256 + threadIdx.x;
    float4 xv = ((const float4*)x)[i];
    float4 ov = ((const float4*)orig)[i];
    int t = i >> 8, c4 = (i & 255) * 4;
    bf16* px = xcat + (size_t)t * 2048 + c4;
    px[0] = f2b(xv.x); px[1] = f2b(xv.y); px[2] = f2b(xv.z); px[3] = f2b(xv.w);
    bf16* po = px + 1024;
    po[0] = f2b(ov.x); po[1] = f2b(ov.y); po[2] = f2b(ov.z); po[3] = f2b(ov.w);
}

// ---------------------------------------------------------------------------
// V transpose: qkv (T,3072) v-part -> Vt (B,H,64,S) bf16
// ---------------------------------------------------------------------------
__global__ __launch_bounds__(256)
void vtrans_kernel(const bf16* __restrict__ qkv, bf16* __restrict__ Vt)
{
    __shared__ float t[32][33];
    const int blk = blockIdx.x;
    const int dt = blk & 1;
    const int st = (blk >> 1) & 31;
    const int h  = (blk >> 6) & 15;
    const int b  = blk >> 10;
    const int tx = threadIdx.x & 31, ty = threadIdx.x >> 5;
    #pragma unroll
    for (int i = 0; i < 4; ++i)
        t[ty + i * 8][tx] = b2f(qkv[(size_t)(b * SEQ + st * 32 + ty + i * 8) * 3072
                                    + 2048 + h * 64 + dt * 32 + tx]);
    __syncthreads();
    #pragma unroll
    for (int i = 0; i < 4; ++i)
        Vt[(size_t)((b * NH + h) * 64 + dt * 32 + ty + i * 8) * SEQ + st * 32 + tx]
            = f2b(t[tx][ty + i * 8]);
}

// ---------------------------------------------------------------------------
// MFMA flash attention, R19: QBLK=128 (R15's geometry lever applied to attn).
//   - grid halves to 512 (b,h,qt): K/V staging bytes + barriers per Q-row
//     halve; each Vs fragment read feeds 2 MFMAs (row-groups g=0,1).
//   - separate P buffer (no KPs alias) -> no mid-iteration cross-wave
//     barrier: 2 barriers/iter instead of 3. P is wave-local (lgkm-ordered).
//   - per wave: 32 q-rows as 2 sequential row-groups (accS regs reused).
//   LDS: KPs 16K + Vs 16K + Ps 32K + relb 4.6K = 68.6K -> 2 blocks/CU.
// (R10 features kept: static-max softmax, __expf, LDS relb, setprio.)
// ---------------------------------------------------------------------------
__global__ __launch_bounds__(256)
void fattn_kernel(const bf16* __restrict__ qkv, const bf16* __restrict__ Vt,
                  const float* __restrict__ relb, bf16* __restrict__ out)
{
    __shared__ bf16 KPs[128 * 64];
    __shared__ bf16 Vs [64 * 128];
    __shared__ bf16 Ps [4 * 32 * 128];
    __shared__ float relb_s[1152];

    const int tid  = threadIdx.x;
    const int lane = tid & 63;
    const int w    = tid >> 6;
    const int fr   = lane & 15;
    const int quad = lane >> 4;

    const int qt = blockIdx.x & 7;
    const int h  = (blockIdx.x >> 3) & 15;
    const int b  = blockIdx.x >> 7;
    const int bq = b * SEQ;
    const int bh = b * NH + h;

    // rel-pos bias slice for this 128-row q-tile, static-max shift folded in.
    // needed indices: (local qi 0..127) - kj + 1023, kj in [0,1024) ->
    // relb[qt*128 .. qt*128+1150]
    for (int i = tid; i < 1151; i += 256)
        relb_s[i] = relb[qt * 128 + i] - 8.0f;

    // Q fragments: 2 row-groups x 2 k-halves
    short8 qf[2][2];
    #pragma unroll
    for (int g = 0; g < 2; ++g) {
        const bf16* qp = qkv + (size_t)(bq + qt * 128 + w * 32 + g * 16 + fr) * 3072
                         + h * 64 + quad * 8;
        qf[g][0] = *(const short8*)(qp);
        qf[g][1] = *(const short8*)(qp + 32);
    }

    int ibase[2][4];
    #pragma unroll
    for (int g = 0; g < 2; ++g)
        #pragma unroll
        for (int r = 0; r < 4; ++r)
            ibase[g][r] = (w * 32 + g * 16 + quad * 4 + r) - fr + 1023;

    float lsum[2][4] = {};
    floatx4 accO[2][4];
    #pragma unroll
    for (int g = 0; g < 2; ++g)
        #pragma unroll
        for (int nt = 0; nt < 4; ++nt) accO[g][nt] = (floatx4){0.f, 0.f, 0.f, 0.f};

    bf16* Pw = Ps + w * (32 * 128);

    for (int k0 = 0; k0 < SEQ; k0 += 128) {
        __syncthreads();              // WAR: all waves done reading KPs/Vs
        #pragma unroll
        for (int it = 0; it < 4; ++it) {
            int s = it * 256 + tid;
            int key = s >> 3, cs = s & 7;
            int c = cs ^ (key & 7);
            const bf16* src = qkv + (size_t)(bq + k0 + key) * 3072 + 1024 + h * 64 + c * 8;
            gload_lds16(src, KPs + (size_t)s * 8);
        }
        #pragma unroll
        for (int it = 0; it < 4; ++it) {
            int s = it * 256 + tid;
            int row = s >> 4, cs = s & 15;
            int c = cs ^ (row & 15);
            const bf16* src = Vt + (size_t)(bh * 64 + row) * SEQ + k0 + c * 8;
            gload_lds16(src, Vs + (size_t)s * 8);
        }
        __syncthreads();              // RAW: tiles resident (vmcnt(0) drain)

        // ---- QK^T + softmax per row-group (P wave-local, no barrier)
        #pragma unroll
        for (int g = 0; g < 2; ++g) {
            floatx4 accS[8];
            #pragma unroll
            for (int t = 0; t < 8; ++t) accS[t] = (floatx4){0.f, 0.f, 0.f, 0.f};
            __builtin_amdgcn_s_setprio(1);
            #pragma unroll
            for (int t = 0; t < 8; ++t) {
                int row = t * 16 + fr;
                #pragma unroll
                for (int ks = 0; ks < 2; ++ks) {
                    int slot = (ks * 4 + quad) ^ (row & 7);
                    short8 kf = *(const short8*)(KPs + (size_t)row * 64 + slot * 8);
                    accS[t] = __builtin_amdgcn_mfma_f32_16x16x32_bf16(qf[g][ks], kf, accS[t], 0, 0, 0);
                }
            }
            __builtin_amdgcn_s_setprio(0);

            #pragma unroll
            for (int t = 0; t < 8; ++t) {
                int keyl = t * 16 + fr;
                int cbase = keyl >> 3, koff = keyl & 7;
                #pragma unroll
                for (int r = 0; r < 4; ++r) {
                    float bias = relb_s[ibase[g][r] - k0 - t * 16];
                    float p = __expf(fmaf(accS[t][r], 0.125f, bias));
                    lsum[g][r] += p;
                    int row = g * 16 + quad * 4 + r;
                    int slot = cbase ^ (row & 15);
                    Pw[(size_t)row * 128 + slot * 8 + koff] = f2b(p);
                }
            }
        }

        // ---- PV: each vf read feeds both row-groups
        __builtin_amdgcn_s_setprio(1);
        #pragma unroll
        for (int ks = 0; ks < 4; ++ks) {
            int slotp = (ks * 4 + quad) ^ (fr & 15);
            short8 pf0 = *(const short8*)(Pw + (size_t)fr * 128 + slotp * 8);
            short8 pf1 = *(const short8*)(Pw + (size_t)(16 + fr) * 128 + slotp * 8);
            #pragma unroll
            for (int nt = 0; nt < 4; ++nt) {
                int vrow = nt * 16 + fr;
                int slotv = (ks * 4 + quad) ^ (vrow & 15);
                short8 vf = *(const short8*)(Vs + (size_t)vrow * 128 + slotv * 8);
                accO[0][nt] = __builtin_amdgcn_mfma_f32_16x16x32_bf16(pf0, vf, accO[0][nt], 0, 0, 0);
                accO[1][nt] = __builtin_amdgcn_mfma_f32_16x16x32_bf16(pf1, vf, accO[1][nt], 0, 0, 0);
            }
        }
        __builtin_amdgcn_s_setprio(0);
    }

    float inv[2][4];
    #pragma unroll
    for (int g = 0; g < 2; ++g)
        #pragma unroll
        for (int r = 0; r < 4; ++r) {
            float v = lsum[g][r];
            v += __shfl_xor(v, 1); v += __shfl_xor(v, 2);
            v += __shfl_xor(v, 4); v += __shfl_xor(v, 8);
            inv[g][r] = 1.0f / v;
        }

    #pragma unroll
    for (int g = 0; g < 2; ++g)
        #pragma unroll
        for (int nt = 0; nt < 4; ++nt) {
            int col = h * 64 + nt * 16 + fr;
            #pragma unroll
            for (int r = 0; r < 4; ++r) {
                int t = bq + qt * 128 + w * 32 + g * 16 + quad * 4 + r;
                out[(size_t)t * D_MODEL + col] = f2b(accO[g][nt][r] * inv[g][r]);
            }
        }
}

// ---------------------------------------------------------------------------
// Fused residual + LayerNorm (optionally sums TWO fp32 add-terms: split-K)
// ---------------------------------------------------------------------------
template<bool OUT_BF16, bool HAS2>
__global__ __launch_bounds__(256)
void ln_kernel(const bf16* __restrict__ a, const float* __restrict__ add,
               const float* __restrict__ add2,
               const float* __restrict__ g, const float* __restrict__ bb,
               void* __restrict__ outv)
{
    __shared__ float red[256];
    __shared__ float red2[256];
    const int row = blockIdx.x;
    const int tid = threadIdx.x;
    float s[4];
    float lsum = 0.f, lsq = 0.f;
    #pragma unroll
    for (int u = 0; u < 4; ++u) {
        int i = tid + 256 * u;
        float v = b2f(a[row * D_MODEL + i]) + add[row * D_MODEL + i];
        if (HAS2) v += add2[row * D_MODEL + i];
        s[u] = v; lsum += v; lsq += v * v;
    }
    red[tid] = lsum; red2[tid] = lsq; __syncthreads();
    for (int s2 = 128; s2 > 0; s2 >>= 1) {
        if (tid < s2) { red[tid] += red[tid + s2]; red2[tid] += red2[tid + s2]; }
        __syncthreads();
    }
    float mean = red[0] * (1.0f / D_MODEL);
    float var  = red2[0] * (1.0f / D_MODEL) - mean * mean;
    float rs = rsqrtf(var + 1e-5f);
    #pragma unroll
    for (int u = 0; u < 4; ++u) {
        int i = tid + 256 * u;
        float o = (s[u] - mean) * rs * g[i] + bb[i];
        if (OUT_BF16) ((bf16*)outv)[row * D_MODEL + i] = f2b(o);
        else          ((float*)outv)[row * D_MODEL + i] = o;
    }
}

// ---------------------------------------------------------------------------
extern "C" void kernel_launch(void* const* d_in, const int* in_sizes, int n_in,
                              void* d_out, int out_size, void* d_ws, size_t ws_size,
                              hipStream_t stream)
{
    const float* x     = (const float*)d_in[0];
    const float* orig  = (const float*)d_in[1];
    const int*   step  = (const int*)  d_in[2];
    const float* se    = (const float*)d_in[3];
    const float* Wqkv  = (const float*)d_in[4];
    const float* bqkv  = (const float*)d_in[5];
    const float* Wout  = (const float*)d_in[6];
    const float* bout  = (const float*)d_in[7];
    const float* Wg    = (const float*)d_in[8];
    const float* bg    = (const float*)d_in[9];
    const float* relb  = (const float*)d_in[10];
    const float* W1    = (const float*)d_in[11];
    const float* b1    = (const float*)d_in[12];
    const float* W2    = (const float*)d_in[13];
    const float* b2    = (const float*)d_in[14];
    const float* ln1g  = (const float*)d_in[15];
    const float* ln1b  = (const float*)d_in[16];
    const float* ln2g  = (const float*)d_in[17];
    const float* ln2b  = (const float*)d_in[18];

    // Workspace layout (76 MB) — lifetimes verified against kernel timeline:
    //   0-4   WgT   (r: gate)          | tmp2 0-16 (w: FFN-down, r: LN2)
    //   4-10  WqkvT (r: QKV)           |   -> all those regions dead by then
    //   10-12 WoutT (r: Wout-proj)
    //   12-20 W1T   (r: FFN-up)
    //   20-28 W2T   (r: FFN-down; NOT overlapped by tmp2)
    //   28-36 xw    (w: gate-epi; rw: LN1; r: QKV, FFN-up, LN2)
    //   36-52 xcat  (w: xcat; r: gate)  | attnb 36-44 (w: fattn, r: Wout)
    //   44-76 h     (w: FFN-up, r: FFN-down; overlaps qkvb after its last read)
    //   52-76 qkvb  (w: QKV; r: vtrans, fattn)
    //   Vt = d_out  (w: vtrans, r: fattn; then tmp from Wout on)
    char* ws = (char*)d_ws;
    bf16* WgT   = (bf16*)(ws);
    bf16* WqkvT = (bf16*)(ws + ( 4u << 20));
    bf16* WoutT = (bf16*)(ws + (10u << 20));
    bf16* W1T   = (bf16*)(ws + (12u << 20));
    bf16* W2T   = (bf16*)(ws + (20u << 20));
    bf16* xw    = (bf16*)(ws + (28u << 20));
    bf16* xcat  = (bf16*)(ws + (36u << 20));
    bf16* attnb = (bf16*)(ws + (36u << 20));
    bf16* h     = (bf16*)(ws + (44u << 20));
    bf16* qkvb  = (bf16*)(ws + (52u << 20));
    float* tmp2 = (float*)(ws);
    bf16* Vt    = (bf16*)d_out;
    float* tmp  = (float*)d_out;

    dim3 blk(256);

    // 0. all weight transposes in one launch + xcat build
    transpose_all_kernel<<<NTRANS_BLOCKS, blk, 0, stream>>>(Wg, WgT, Wqkv, WqkvT,
                                                    Wout, WoutT, W1, W1T, W2, W2T);
    xcat_kernel<<<TOK, blk, 0, stream>>>(x, orig, xcat);

    // 1. gate GEMM (A = xcat via async LDS-DMA) + gatemix epilogue -> xw
    mfma_gemm<64, 3, false><<<dim3(D_MODEL/64, TOK/128), blk, 0, stream>>>(
        xcat, WgT, bg, xw, nullptr, TOK, D_MODEL, 2*D_MODEL, 2*D_MODEL, 2*D_MODEL,
        x, orig, se, step);

    // 2. QKV projection -> qkvb   [wide 256x128 tile, grid 24x16]
    gemm_wide<1><<<dim3(3*D_MODEL/128, TOK/256), blk, 0, stream>>>(
        xw, WqkvT, bqkv, qkvb, TOK, 3*D_MODEL, D_MODEL);

    // 3a. V transpose -> Vt (= d_out scratch)
    vtrans_kernel<<<BATCH*NH*64, blk, 0, stream>>>(qkvb, Vt);

    // 3b. MFMA flash attention -> attnb   [R19: QBLK=128, grid 512]
    fattn_kernel<<<BATCH*NH*(SEQ/128), blk, 0, stream>>>(qkvb, Vt, relb, attnb);

    // 4. output projection -> tmp (fp32, overwrites Vt scratch)
    mfma_gemm<64, 0, false><<<dim3(D_MODEL/64, TOK/128), blk, 0, stream>>>(
        attnb, WoutT, bout, tmp, nullptr, TOK, D_MODEL, D_MODEL, D_MODEL, D_MODEL,
        nullptr, nullptr, nullptr, nullptr);

    // 5. LN1(xw + tmp) -> xw (bf16, in place)
    ln_kernel<true, false><<<TOK, blk, 0, stream>>>(xw, tmp, nullptr, ln1g, ln1b, xw);

    // 6. FFN up + exact GELU -> h   [wide 256x128 tile, grid 32x16]
    gemm_wide<2><<<dim3(DFF/128, TOK/256), blk, 0, stream>>>(
        xw, W1T, b1, h, TOK, DFF, D_MODEL);

    // 7. FFN down, split-K=2, TN=128 -> tmp (z=0) + tmp2 (z=1)
    mfma_gemm<128, 0, true><<<dim3(D_MODEL/128, TOK/128, 2), blk, 0, stream>>>(
        h, W2T, b2, tmp, tmp2, TOK, D_MODEL, DFF/2, DFF, DFF,
        nullptr, nullptr, nullptr, nullptr);

    // 8. LN2(xw + tmp + tmp2) -> d_out (fp32, in place over tmp)
    ln_kernel<false, true><<<TOK, blk, 0, stream>>>(xw, tmp, tmp2, ln2g, ln2b, d_out);
}